// Round 5
// baseline (247.315 us; speedup 1.0000x reference)
//
#include <hip/hip_runtime.h>
#include <math.h>

// Problem constants (match reference)
#define NNODES 50000
#define NEDGES 800000
#define INF 128
#define OUTF 128
#define HEADS 2
#define NEG_SLOPE 0.2f

// Per-XCD private bins: edge e with dst d running on XCD x claims a slot in
// bin[d][x][0..SCAPX) via a WORKGROUP-scope atomic (executes in the local
// XCD's L2 -- no Infinity-Fabric round trip; only same-XCD blocks touch a
// given cursor/bin line, so L2-local atomicity is sufficient; kernel-end
// writeback publishes). deg ~ Poisson(16) -> per-XCD ~ Poisson(2);
// P(>8) ~ 2e-4 per (node,xcd) -> ~80 edges chip-wide go to the exact ovf list.
// A compact pass then merges the 8 prefixes into a dense <=32 bin in-place.
#define NXCD 8
#define SCAPX 8          // slots per (node, xcd)
#define NSLOT 64         // NXCD * SCAPX, per-node region (512 B, line-aligned per xcd)
#define DCAP 32          // dense bin cap after compaction (deg>32: P~1.5e-4 -> ovf)
#define OVFCAP 32768
#define OVFFLAG 0x40000000

__device__ __forceinline__ unsigned short f2bf(float f) {
    unsigned u = __float_as_uint(f);
    unsigned r = (u + 0x7FFFu + ((u >> 16) & 1u)) >> 16;   // RNE
    return (unsigned short)r;
}
__device__ __forceinline__ float bf2f(unsigned short b) {
    return __uint_as_float((unsigned)b << 16);
}
// 2x f32 -> packed bf16 (1 VALU op instead of ~6; T12 recipe)
__device__ __forceinline__ unsigned cvt_pk_bf16(float lo, float hi) {
    unsigned r;
    asm("v_cvt_pk_bf16_f32 %0, %1, %2" : "=v"(r) : "v"(lo), "v"(hi));
    return r;
}

typedef __attribute__((ext_vector_type(8))) short frag_ab;   // 8 bf16 (4 VGPRs)
typedef __attribute__((ext_vector_type(4))) float frag_cd;   // 4 fp32 acc
typedef __attribute__((ext_vector_type(8))) unsigned short ushort8v;

#define APITCH 136   // halfs per padded LDS row (272 B)

// ---------- K0: init scratch + one-time param prep ----------
// blocks [0, zblk): zero 8N per-XCD cursors + ovfcnt (contiguous)
// block  zblk     : wfold[vq][128]  vq=0,1: attn_l-folded W per head; 2,3: attn_r
// blocks zblk+1..+8 : Wb = bf16(W)  (32768 elems)
__global__ void init_kernel(int* cur8, int* /*ovfcnt is cur8+8N*/,
                            const float* __restrict__ W,
                            const float* __restrict__ attn_l,
                            const float* __restrict__ attn_r,
                            unsigned short* __restrict__ Wb,
                            float* __restrict__ wfold, int N) {
    const int b = blockIdx.x, t = threadIdx.x;
    const int zn = NXCD * N + 1;
    const int zblk = (zn + 255) >> 8;
    if (b < zblk) {
        int i = b * 256 + t;
        if (i < zn) cur8[i] = 0;
        return;
    }
    if (b == zblk) {
        // el[n,h] = feat[n]·wfold[h], er[n,h] = feat[n]·wfold[2+h]
        int h = t >> 7, f = t & 127;
        float sl = 0.f, sr = 0.f;
#pragma unroll 16
        for (int o = 0; o < 128; ++o) {
            float wv = W[(size_t)(h * 128 + o) * 128 + f];
            sl = fmaf(attn_l[h * 128 + o], wv, sl);
            sr = fmaf(attn_r[h * 128 + o], wv, sr);
        }
        wfold[h * 128 + f] = sl;
        wfold[(2 + h) * 128 + f] = sr;
        return;
    }
    int base = (b - zblk - 1) * 4096 + t * 16;
#pragma unroll
    for (int q = 0; q < 4; ++q) {
        float4 g = *(const float4*)(W + base + q * 4);
        ushort4 v; v.x = f2bf(g.x); v.y = f2bf(g.y); v.z = f2bf(g.z); v.w = f2bf(g.w);
        *(ushort4*)(Wb + base + q * 4) = v;
    }
}

// ---------- K1: MFMA gemm, LDS-staged B, SWAPPED operands ----------
// 128 nodes/block (2 row-groups per wave): B-stage traffic halves and each
// ds_read_b128 feeds 2 MFMAs; 391 blocks all co-resident (2 blocks/CU).
// SWAPPED mfma(bf, af): operand layouts are symmetric (m16 = non-K index,
// quad*8+e = K), so swapping makes D[row=W-j quad*4+reg][col=node m16] --
// a lane holds 4 CONSECUTIVE j of ONE node row -> ushort4 (8B) stores via
// 2x v_cvt_pk_bf16_f32, replacing r4's 64 scalar 2B stores + 192 cvt VALU.
// el/er: exact fp32 dots feat·wfold on the A floats (pre-barrier, overlaps
// the LDS staging).
__global__ __launch_bounds__(256) void gemm_mfma(const float* __restrict__ feat,
                                                 const unsigned short* __restrict__ Wb,
                                                 const float* __restrict__ wfold,
                                                 unsigned short* __restrict__ ftb,
                                                 float* __restrict__ el,
                                                 float* __restrict__ er,
                                                 int N) {
    __shared__ unsigned short Bs[256 * APITCH];   // 69,632 B -> 2 blocks/CU
    const int t = threadIdx.x;
    const int w = t >> 6, lane = t & 63;
    const int m16 = lane & 15, quad = lane >> 4;
    const int n0 = blockIdx.x * 128;
    const int r0 = n0 + w * 16 + m16;          // row-group 0 node
    const int r1 = r0 + 64;                    // row-group 1 node
    const bool v0 = r0 < N, v1 = r1 < N;

    // stage Wb -> Bs, coalesced: 4096 16B-chunks, 16 per thread
#pragma unroll
    for (int i = 0; i < 16; ++i) {
        int q = t + i * 256;             // chunk id 0..4095
        int row = q >> 4, c = q & 15;    // row 0..255, 16B chunk 0..15
        ushort8v v = *(const ushort8v*)(Wb + row * 128 + c * 8);
        *(ushort8v*)(&Bs[row * APITCH + c * 8]) = v;
    }

    frag_ab af[2][4];
    float pd[2][4] = {{0.f, 0.f, 0.f, 0.f}, {0.f, 0.f, 0.f, 0.f}};
#pragma unroll
    for (int kc = 0; kc < 4; ++kc) {
        const int cc = kc * 32 + quad * 8;
        float4 ga0 = make_float4(0.f, 0.f, 0.f, 0.f), ga1 = ga0;
        float4 gb0 = ga0, gb1 = ga0;
        if (v0) {
            ga0 = *(const float4*)(feat + (size_t)r0 * INF + cc);
            ga1 = *(const float4*)(feat + (size_t)r0 * INF + cc + 4);
        }
        if (v1) {
            gb0 = *(const float4*)(feat + (size_t)r1 * INF + cc);
            gb1 = *(const float4*)(feat + (size_t)r1 * INF + cc + 4);
        }
        union { int4 i; frag_ab f; } ua, ub;
        ua.i.x = (int)cvt_pk_bf16(ga0.x, ga0.y); ua.i.y = (int)cvt_pk_bf16(ga0.z, ga0.w);
        ua.i.z = (int)cvt_pk_bf16(ga1.x, ga1.y); ua.i.w = (int)cvt_pk_bf16(ga1.z, ga1.w);
        ub.i.x = (int)cvt_pk_bf16(gb0.x, gb0.y); ub.i.y = (int)cvt_pk_bf16(gb0.z, gb0.w);
        ub.i.z = (int)cvt_pk_bf16(gb1.x, gb1.y); ub.i.w = (int)cvt_pk_bf16(gb1.z, gb1.w);
        af[0][kc] = ua.f; af[1][kc] = ub.f;
#pragma unroll
        for (int vq = 0; vq < 4; ++vq) {
            float4 w0 = *(const float4*)(wfold + vq * 128 + cc);
            float4 w1 = *(const float4*)(wfold + vq * 128 + cc + 4);
            pd[0][vq] += ga0.x * w0.x + ga0.y * w0.y + ga0.z * w0.z + ga0.w * w0.w
                       + ga1.x * w1.x + ga1.y * w1.y + ga1.z * w1.z + ga1.w * w1.w;
            pd[1][vq] += gb0.x * w0.x + gb0.y * w0.y + gb0.z * w0.z + gb0.w * w0.w
                       + gb1.x * w1.x + gb1.y * w1.y + gb1.z * w1.z + gb1.w * w1.w;
        }
    }
    // reduce over the 4 quads (xor 16,32)
#pragma unroll
    for (int m = 16; m < 64; m <<= 1)
#pragma unroll
        for (int rg = 0; rg < 2; ++rg)
#pragma unroll
            for (int vq = 0; vq < 4; ++vq) pd[rg][vq] += __shfl_xor(pd[rg][vq], m, 64);
    if (quad == 0) {
        if (v0) {
            *(float2*)(el + (size_t)r0 * 2) = make_float2(pd[0][0], pd[0][1]);
            *(float2*)(er + (size_t)r0 * 2) = make_float2(pd[0][2], pd[0][3]);
        }
        if (v1) {
            *(float2*)(el + (size_t)r1 * 2) = make_float2(pd[1][0], pd[1][1]);
            *(float2*)(er + (size_t)r1 * 2) = make_float2(pd[1][2], pd[1][3]);
        }
    }

    __syncthreads();   // Bs ready

#pragma unroll 1
    for (int jt = 0; jt < 4; ++jt) {
        frag_cd acc[2][4];
#pragma unroll
        for (int rg = 0; rg < 2; ++rg)
#pragma unroll
            for (int nt = 0; nt < 4; ++nt) acc[rg][nt] = frag_cd{0.f, 0.f, 0.f, 0.f};
#pragma unroll
        for (int kc = 0; kc < 4; ++kc)
#pragma unroll
            for (int nt = 0; nt < 4; ++nt) {
                frag_ab bf = *(const frag_ab*)(&Bs[(jt * 64 + nt * 16 + m16) * APITCH
                                                   + kc * 32 + quad * 8]);
                acc[0][nt] = __builtin_amdgcn_mfma_f32_16x16x32_bf16(bf, af[0][kc],
                                                                     acc[0][nt], 0, 0, 0);
                acc[1][nt] = __builtin_amdgcn_mfma_f32_16x16x32_bf16(bf, af[1][kc],
                                                                     acc[1][nt], 0, 0, 0);
            }
        // epilogue: lane holds j = jt*64 + nt*16 + quad*4 + (0..3) of node row
#pragma unroll
        for (int rg = 0; rg < 2; ++rg) {
            const int rr = rg ? r1 : r0;
            if (rg ? v1 : v0) {
#pragma unroll
                for (int nt = 0; nt < 4; ++nt) {
                    uint2 p;
                    p.x = cvt_pk_bf16(acc[rg][nt][0], acc[rg][nt][1]);
                    p.y = cvt_pk_bf16(acc[rg][nt][2], acc[rg][nt][3]);
                    *(uint2*)(ftb + (size_t)rr * 256 + jt * 64 + nt * 16 + quad * 4) = p;
                }
            }
        }
    }
}

// ---------- K2: fused edge logits + leaky_relu + exp + XCD-local scatter ----------
// No segment-max (softmax shift-invariant; logits O(10), exp safe in fp32).
__global__ __launch_bounds__(256) void edge_fused(const float* __restrict__ el,
                           const float* __restrict__ er,
                           const float* __restrict__ e_w, const int* __restrict__ src,
                           const int* __restrict__ dst, const float* __restrict__ attn_ew,
                           int* __restrict__ cur8, int* __restrict__ ovfcnt,
                           uint2* __restrict__ bins, float4* __restrict__ ovf,
                           int E) {
    int e = blockIdx.x * 256 + threadIdx.x;
    if (e >= E) return;
    unsigned xcc;
    asm volatile("s_getreg_b32 %0, hwreg(HW_REG_XCC_ID)" : "=s"(xcc));
    xcc &= (NXCD - 1);
    int s = src[e], d = dst[e];
    float2 ew2 = *(const float2*)(e_w + (size_t)e * 2);
    float2 elv = *(const float2*)(el + (size_t)s * 2);
    float2 erv = *(const float2*)(er + (size_t)d * 2);
    float v0 = elv.x + erv.x + ew2.x * attn_ew[0] + ew2.y * attn_ew[1];
    float v1 = elv.y + erv.y + ew2.x * attn_ew[2] + ew2.y * attn_ew[3];
    v0 = v0 >= 0.f ? v0 : NEG_SLOPE * v0;
    v1 = v1 >= 0.f ? v1 : NEG_SLOPE * v1;
    float ee0 = __expf(v0);
    float ee1 = __expf(v1);
    // workgroup-scope atomic: executes in this XCD's L2; only same-XCD blocks
    // touch cur8[d*8+xcc], so L2-local atomicity is sufficient.
    int pos = __hip_atomic_fetch_add(cur8 + (size_t)d * NXCD + xcc, 1,
                                     __ATOMIC_RELAXED, __HIP_MEMORY_SCOPE_WORKGROUP);
    if (pos < SCAPX) {
        unsigned pk = ((unsigned)f2bf(ee1) << 16) | (unsigned)f2bf(ee0);
        bins[(size_t)d * NSLOT + xcc * SCAPX + pos] = make_uint2((unsigned)s, pk);
    } else {
        int o = atomicAdd(ovfcnt, 1);
        if (o < OVFCAP)
            ovf[o] = make_float4(__int_as_float(d), __int_as_float(s), ee0, ee1);
    }
}

// ---------- K2b: compact the 8 per-XCD prefixes into one dense bin ----------
// Wave per node: 64 lanes read the node's 64 slots (coalesced 512B), ballot
// valid slots, popcount-prefix gives each valid rec its dense position,
// write back in-place (all loads precede stores in wave program order).
__global__ __launch_bounds__(256) void compact_bins(uint2* __restrict__ bins,
                                                    const int* __restrict__ cur8,
                                                    int* __restrict__ cntd,
                                                    int* __restrict__ ovfcnt,
                                                    float4* __restrict__ ovf, int N) {
    const int t = threadIdx.x;
    const int w = t >> 6, l = t & 63;
    const int n = blockIdx.x * 4 + w;
    if (n >= N) return;
    const int x = l >> 3, slot = l & 7;
    const int cx = cur8[(size_t)n * NXCD + x];     // raw (uncapped) count
    uint2 rec = bins[(size_t)n * NSLOT + l];
    const int cxc = cx < SCAPX ? cx : SCAPX;
    const bool valid = slot < cxc;
    unsigned long long mask = __ballot(valid);
    int pos = __popcll(mask & ((1ull << l) - 1ull));
    int tot = __popcll(mask);
    bool oflag = __any(slot == 0 && cx > SCAPX) || (tot > DCAP);
    if (valid) {
        if (pos < DCAP) {
            bins[(size_t)n * NSLOT + pos] = rec;
        } else {   // dense bin full -> exact path (deg>32, ~1e-4 of nodes)
            int o = atomicAdd(ovfcnt, 1);
            if (o < OVFCAP)
                ovf[o] = make_float4(__int_as_float(n), __int_as_float((int)rec.x),
                                     bf2f((unsigned short)(rec.y & 0xFFFFu)),
                                     bf2f((unsigned short)(rec.y >> 16)));
        }
    }
    if (l == 0) cntd[n] = (tot < DCAP ? tot : DCAP) | (oflag ? OVFFLAG : 0);
}

// ---------- K3: wave-per-node gather-aggregate + normalize + residual + elu ----------
// Half-wave edge split (hl covers 8 cols via one ushort8; lower half even edges,
// upper half odd) + unroll 8. Dense bin -> no index remap in the address chain.
__global__ __launch_bounds__(256) void aggregate(const unsigned short* __restrict__ ftb,
                                                 const float* __restrict__ feat,
                                                 const uint2* __restrict__ bins,
                                                 const int* __restrict__ cntd,
                                                 const int* __restrict__ ovfcnt,
                                                 const float4* __restrict__ ovf,
                                                 float* __restrict__ out, int N) {
    const int t = threadIdx.x;
    const int w = t >> 6, l = t & 63;
    const int n = blockIdx.x * 4 + w;
    if (n >= N) return;
    const int hl = l & 31;           // half-lane id
    const int half = l >> 5;         // 0: even edges, 1: odd edges
    const int c8 = 8 * hl;           // 8-col base this half-lane covers
    const int h = hl >> 4;           // head for these cols
    const int cw = cntd[n];
    const int cnt = cw & 0xFFFF;
    const uint2* eb = bins + (size_t)n * NSLOT;

    float4 a0 = make_float4(0.f, 0.f, 0.f, 0.f);
    float4 a1 = make_float4(0.f, 0.f, 0.f, 0.f);
    float dn = 0.f;
    const int hm = (cnt + 1) >> 1;
#pragma unroll 8
    for (int i = 0; i < hm; ++i) {
        const int j = 2 * i + half;
        const bool vld = j < cnt;
        uint2 rec = eb[vld ? j : 0];
        float aw = bf2f((unsigned short)(h ? (rec.y >> 16) : (rec.y & 0xFFFFu)));
        float a = vld ? aw : 0.f;
        unsigned su = vld ? rec.x : 0u;
        ushort8v v = *(const ushort8v*)(ftb + (size_t)su * 256 + c8);
        dn += a;
        a0.x = fmaf(a, bf2f(v[0]), a0.x);
        a0.y = fmaf(a, bf2f(v[1]), a0.y);
        a0.z = fmaf(a, bf2f(v[2]), a0.z);
        a0.w = fmaf(a, bf2f(v[3]), a0.w);
        a1.x = fmaf(a, bf2f(v[4]), a1.x);
        a1.y = fmaf(a, bf2f(v[5]), a1.y);
        a1.z = fmaf(a, bf2f(v[6]), a1.z);
        a1.w = fmaf(a, bf2f(v[7]), a1.w);
    }
    // combine even/odd halves (lanes l and l^32 cover the same 8 cols)
    a0.x += __shfl_xor(a0.x, 32, 64);
    a0.y += __shfl_xor(a0.y, 32, 64);
    a0.z += __shfl_xor(a0.z, 32, 64);
    a0.w += __shfl_xor(a0.w, 32, 64);
    a1.x += __shfl_xor(a1.x, 32, 64);
    a1.y += __shfl_xor(a1.y, 32, 64);
    a1.z += __shfl_xor(a1.z, 32, 64);
    a1.w += __shfl_xor(a1.w, 32, 64);
    dn += __shfl_xor(dn, 32, 64);

    if (cw & OVFFLAG) {   // exact overflow path (rare); all lanes add identically
        int no = *ovfcnt; if (no > OVFCAP) no = OVFCAP;
        for (int i = 0; i < no; ++i) {
            float4 ov = ovf[i];
            if (__float_as_int(ov.x) == n) {
                int s = __float_as_int(ov.y);
                float a = h ? ov.w : ov.z;
                dn += a;
                ushort8v v = *(const ushort8v*)(ftb + (size_t)s * 256 + c8);
                a0.x = fmaf(a, bf2f(v[0]), a0.x);
                a0.y = fmaf(a, bf2f(v[1]), a0.y);
                a0.z = fmaf(a, bf2f(v[2]), a0.z);
                a0.w = fmaf(a, bf2f(v[3]), a0.w);
                a1.x = fmaf(a, bf2f(v[4]), a1.x);
                a1.y = fmaf(a, bf2f(v[5]), a1.y);
                a1.z = fmaf(a, bf2f(v[6]), a1.z);
                a1.w = fmaf(a, bf2f(v[7]), a1.w);
            }
        }
    }
    float inv = dn > 0.f ? 1.0f / dn : 0.f;
    const int cb = c8 + 4 * half;            // this lane's 4 output cols
    float4 av = half ? a1 : a0;
    float4 f4 = *(const float4*)(feat + (size_t)n * INF + (cb & 127));
    float4 r;
    r.x = fmaf(av.x, inv, f4.x);
    r.y = fmaf(av.y, inv, f4.y);
    r.z = fmaf(av.z, inv, f4.z);
    r.w = fmaf(av.w, inv, f4.w);
    r.x = r.x > 0.f ? r.x : expm1f(r.x);
    r.y = r.y > 0.f ? r.y : expm1f(r.y);
    r.z = r.z > 0.f ? r.z : expm1f(r.z);
    r.w = r.w > 0.f ? r.w : expm1f(r.w);
    *(float4*)(out + (size_t)n * 256 + cb) = r;
}

extern "C" void kernel_launch(void* const* d_in, const int* in_sizes, int n_in,
                              void* d_out, int out_size, void* d_ws, size_t ws_size,
                              hipStream_t stream) {
    const float* feat    = (const float*)d_in[0];
    const float* e_w     = (const float*)d_in[1];
    const int*   src     = (const int*)d_in[2];
    const int*   dst     = (const int*)d_in[3];
    const float* W       = (const float*)d_in[4];
    const float* attn_l  = (const float*)d_in[5];
    const float* attn_r  = (const float*)d_in[6];
    const float* attn_ew = (const float*)d_in[7];
    float* out = (float*)d_out;

    const int N = in_sizes[0] / INF;   // 50000
    const int E = in_sizes[2];         // 800000

    // workspace carve-up (all offsets 16B-aligned for these sizes; ~54.4 MB)
    unsigned short* ftb = (unsigned short*)d_ws;                 // N*256 bf16   (25.6 MB)
    uint2*  bins   = (uint2*)(ftb + (size_t)N * 256);            // N*64 recs    (25.6 MB)
    float*  el     = (float*)(bins + (size_t)N * NSLOT);         // N*2          (0.4 MB)
    float*  er     = el + (size_t)N * 2;                         // N*2          (0.4 MB)
    float*  wfold  = er + (size_t)N * 2;                         // 4*128 f      (2 KB)
    unsigned short* Wb = (unsigned short*)(wfold + 512);         // 256*128 bf16 (64 KB)
    float4* ovf    = (float4*)(Wb + 32768);                      // OVFCAP       (0.5 MB)
    int*    cur8   = (int*)(ovf + OVFCAP);                       // 8N           (1.6 MB)
    int*    ovfcnt = cur8 + (size_t)NXCD * N;                    // 1 (zeroed with cur8)
    int*    cntd   = ovfcnt + 1;                                 // N (written by compact)

    const int zblk = (NXCD * N + 1 + 255) / 256;
    init_kernel<<<zblk + 9, 256, 0, stream>>>(cur8, ovfcnt, W, attn_l, attn_r, Wb, wfold, N);

    gemm_mfma<<<(N + 127) / 128, 256, 0, stream>>>(feat, Wb, wfold, ftb, el, er, N);

    edge_fused<<<(E + 255) / 256, 256, 0, stream>>>(el, er, e_w, src, dst, attn_ew,
                                                    cur8, ovfcnt, bins, ovf, E);

    compact_bins<<<(N + 3) / 4, 256, 0, stream>>>(bins, cur8, cntd, ovfcnt, ovf, N);

    aggregate<<<(N + 3) / 4, 256, 0, stream>>>(ftb, feat, bins, cntd, ovfcnt, ovf, out, N);
}

// Round 6
// 232.315 us; speedup vs baseline: 1.0646x; 1.0646x over previous
//
#include <hip/hip_runtime.h>
#include <math.h>

// Problem constants (match reference)
#define NNODES 50000
#define NEDGES 800000
#define INF 128
#define OUTF 128
#define HEADS 2
#define NEG_SLOPE 0.2f

// Padded-bin CSR, 2-way sharded cursors (r4-proven): degree ~ Poisson(16)
// split ~8/8 over two shards of 16 slots in one dense 32-record bin.
// Shard-full -> retry sibling; both-full -> exact overflow list.
#define CAP 32
#define SCAP 16
#define OVFCAP 32768

__device__ __forceinline__ unsigned short f2bf(float f) {
    unsigned u = __float_as_uint(f);
    unsigned r = (u + 0x7FFFu + ((u >> 16) & 1u)) >> 16;   // RNE
    return (unsigned short)r;
}
__device__ __forceinline__ float bf2f(unsigned short b) {
    return __uint_as_float((unsigned)b << 16);
}
// 2x f32 -> packed bf16 (1 VALU op; T12 recipe)
__device__ __forceinline__ unsigned cvt_pk_bf16(float lo, float hi) {
    unsigned r;
    asm("v_cvt_pk_bf16_f32 %0, %1, %2" : "=v"(r) : "v"(lo), "v"(hi));
    return r;
}

typedef __attribute__((ext_vector_type(8))) short frag_ab;   // 8 bf16 (4 VGPRs)
typedef __attribute__((ext_vector_type(4))) float frag_cd;   // 4 fp32 acc
typedef __attribute__((ext_vector_type(8))) unsigned short ushort8v;

#define APITCH 136   // halfs per padded LDS row (272 B)

// ---------- K0: init scratch + one-time param prep ----------
// blocks [0, zblk): zero 2N sharded cursors + ovfcnt
// block  zblk     : wfold[vq][128]  vq=0,1: attn_l-folded W per head; 2,3: attn_r
// blocks zblk+1..+8 : Wb = bf16(W)  (32768 elems)
__global__ void init_kernel(int* cursor, int* ovfcnt,
                            const float* __restrict__ W,
                            const float* __restrict__ attn_l,
                            const float* __restrict__ attn_r,
                            unsigned short* __restrict__ Wb,
                            float* __restrict__ wfold, int N) {
    const int b = blockIdx.x, t = threadIdx.x;
    const int zblk = (2 * N + 255) >> 8;
    if (b < zblk) {
        int i = b * 256 + t;
        if (i < 2 * N) cursor[i] = 0;
        if (i == 0) *ovfcnt = 0;
        return;
    }
    if (b == zblk) {
        // el[n,h] = feat[n]·wfold[h], er[n,h] = feat[n]·wfold[2+h]
        int h = t >> 7, f = t & 127;
        float sl = 0.f, sr = 0.f;
#pragma unroll 16
        for (int o = 0; o < 128; ++o) {
            float wv = W[(size_t)(h * 128 + o) * 128 + f];
            sl = fmaf(attn_l[h * 128 + o], wv, sl);
            sr = fmaf(attn_r[h * 128 + o], wv, sr);
        }
        wfold[h * 128 + f] = sl;
        wfold[(2 + h) * 128 + f] = sr;
        return;
    }
    int base = (b - zblk - 1) * 4096 + t * 16;
#pragma unroll
    for (int q = 0; q < 4; ++q) {
        float4 g = *(const float4*)(W + base + q * 4);
        ushort4 v; v.x = f2bf(g.x); v.y = f2bf(g.y); v.z = f2bf(g.z); v.w = f2bf(g.w);
        *(ushort4*)(Wb + base + q * 4) = v;
    }
}

// ---------- K1: MFMA gemm, LDS-staged B, SWAPPED operands (r5, verified) ----------
// 128 nodes/block (2 row-groups/wave): half the blocks/staging of r4.
// SWAPPED mfma(bf, af): lane holds 4 CONSECUTIVE j of ONE node row ->
// uint2 (8B) stores via v_cvt_pk_bf16_f32 (r4 had 64 scalar 2B stores +
// 192 cvt VALU per thread). el/er: exact fp32 dots feat·wfold, pre-barrier.
__global__ __launch_bounds__(256) void gemm_mfma(const float* __restrict__ feat,
                                                 const unsigned short* __restrict__ Wb,
                                                 const float* __restrict__ wfold,
                                                 unsigned short* __restrict__ ftb,
                                                 float* __restrict__ el,
                                                 float* __restrict__ er,
                                                 int N) {
    __shared__ unsigned short Bs[256 * APITCH];   // 69,632 B -> 2 blocks/CU
    const int t = threadIdx.x;
    const int w = t >> 6, lane = t & 63;
    const int m16 = lane & 15, quad = lane >> 4;
    const int n0 = blockIdx.x * 128;
    const int r0 = n0 + w * 16 + m16;          // row-group 0 node
    const int r1 = r0 + 64;                    // row-group 1 node
    const bool v0 = r0 < N, v1 = r1 < N;

    // stage Wb -> Bs, coalesced: 4096 16B-chunks, 16 per thread
#pragma unroll
    for (int i = 0; i < 16; ++i) {
        int q = t + i * 256;             // chunk id 0..4095
        int row = q >> 4, c = q & 15;    // row 0..255, 16B chunk 0..15
        ushort8v v = *(const ushort8v*)(Wb + row * 128 + c * 8);
        *(ushort8v*)(&Bs[row * APITCH + c * 8]) = v;
    }

    frag_ab af[2][4];
    float pd[2][4] = {{0.f, 0.f, 0.f, 0.f}, {0.f, 0.f, 0.f, 0.f}};
#pragma unroll
    for (int kc = 0; kc < 4; ++kc) {
        const int cc = kc * 32 + quad * 8;
        float4 ga0 = make_float4(0.f, 0.f, 0.f, 0.f), ga1 = ga0;
        float4 gb0 = ga0, gb1 = ga0;
        if (v0) {
            ga0 = *(const float4*)(feat + (size_t)r0 * INF + cc);
            ga1 = *(const float4*)(feat + (size_t)r0 * INF + cc + 4);
        }
        if (v1) {
            gb0 = *(const float4*)(feat + (size_t)r1 * INF + cc);
            gb1 = *(const float4*)(feat + (size_t)r1 * INF + cc + 4);
        }
        union { int4 i; frag_ab f; } ua, ub;
        ua.i.x = (int)cvt_pk_bf16(ga0.x, ga0.y); ua.i.y = (int)cvt_pk_bf16(ga0.z, ga0.w);
        ua.i.z = (int)cvt_pk_bf16(ga1.x, ga1.y); ua.i.w = (int)cvt_pk_bf16(ga1.z, ga1.w);
        ub.i.x = (int)cvt_pk_bf16(gb0.x, gb0.y); ub.i.y = (int)cvt_pk_bf16(gb0.z, gb0.w);
        ub.i.z = (int)cvt_pk_bf16(gb1.x, gb1.y); ub.i.w = (int)cvt_pk_bf16(gb1.z, gb1.w);
        af[0][kc] = ua.f; af[1][kc] = ub.f;
#pragma unroll
        for (int vq = 0; vq < 4; ++vq) {
            float4 w0 = *(const float4*)(wfold + vq * 128 + cc);
            float4 w1 = *(const float4*)(wfold + vq * 128 + cc + 4);
            pd[0][vq] += ga0.x * w0.x + ga0.y * w0.y + ga0.z * w0.z + ga0.w * w0.w
                       + ga1.x * w1.x + ga1.y * w1.y + ga1.z * w1.z + ga1.w * w1.w;
            pd[1][vq] += gb0.x * w0.x + gb0.y * w0.y + gb0.z * w0.z + gb0.w * w0.w
                       + gb1.x * w1.x + gb1.y * w1.y + gb1.z * w1.z + gb1.w * w1.w;
        }
    }
    // reduce over the 4 quads (xor 16,32)
#pragma unroll
    for (int m = 16; m < 64; m <<= 1)
#pragma unroll
        for (int rg = 0; rg < 2; ++rg)
#pragma unroll
            for (int vq = 0; vq < 4; ++vq) pd[rg][vq] += __shfl_xor(pd[rg][vq], m, 64);
    if (quad == 0) {
        if (v0) {
            *(float2*)(el + (size_t)r0 * 2) = make_float2(pd[0][0], pd[0][1]);
            *(float2*)(er + (size_t)r0 * 2) = make_float2(pd[0][2], pd[0][3]);
        }
        if (v1) {
            *(float2*)(el + (size_t)r1 * 2) = make_float2(pd[1][0], pd[1][1]);
            *(float2*)(er + (size_t)r1 * 2) = make_float2(pd[1][2], pd[1][3]);
        }
    }

    __syncthreads();   // Bs ready

#pragma unroll 1
    for (int jt = 0; jt < 4; ++jt) {
        frag_cd acc[2][4];
#pragma unroll
        for (int rg = 0; rg < 2; ++rg)
#pragma unroll
            for (int nt = 0; nt < 4; ++nt) acc[rg][nt] = frag_cd{0.f, 0.f, 0.f, 0.f};
#pragma unroll
        for (int kc = 0; kc < 4; ++kc)
#pragma unroll
            for (int nt = 0; nt < 4; ++nt) {
                frag_ab bf = *(const frag_ab*)(&Bs[(jt * 64 + nt * 16 + m16) * APITCH
                                                   + kc * 32 + quad * 8]);
                acc[0][nt] = __builtin_amdgcn_mfma_f32_16x16x32_bf16(bf, af[0][kc],
                                                                     acc[0][nt], 0, 0, 0);
                acc[1][nt] = __builtin_amdgcn_mfma_f32_16x16x32_bf16(bf, af[1][kc],
                                                                     acc[1][nt], 0, 0, 0);
            }
        // epilogue: lane holds j = jt*64 + nt*16 + quad*4 + (0..3) of node row
#pragma unroll
        for (int rg = 0; rg < 2; ++rg) {
            const int rr = rg ? r1 : r0;
            if (rg ? v1 : v0) {
#pragma unroll
                for (int nt = 0; nt < 4; ++nt) {
                    uint2 p;
                    p.x = cvt_pk_bf16(acc[rg][nt][0], acc[rg][nt][1]);
                    p.y = cvt_pk_bf16(acc[rg][nt][2], acc[rg][nt][3]);
                    *(uint2*)(ftb + (size_t)rr * 256 + jt * 64 + nt * 16 + quad * 4) = p;
                }
            }
        }
    }
}

// ---------- K2: fused edge logits + leaky_relu + exp + sharded-bin scatter ----------
// (r4-proven) No segment-max (softmax shift-invariant; logits O(10)).
__global__ void edge_fused(const float* __restrict__ el, const float* __restrict__ er,
                           const float* __restrict__ e_w, const int* __restrict__ src,
                           const int* __restrict__ dst, const float* __restrict__ attn_ew,
                           int* __restrict__ cursor, int* __restrict__ ovfcnt,
                           uint2* __restrict__ edata, float4* __restrict__ ovf,
                           int N, int E) {
    int e = blockIdx.x * 256 + threadIdx.x;
    if (e >= E) return;
    int s = src[e], d = dst[e];
    float2 ew2 = *(const float2*)(e_w + (size_t)e * 2);
    float2 elv = *(const float2*)(el + (size_t)s * 2);
    float2 erv = *(const float2*)(er + (size_t)d * 2);
    float v0 = elv.x + erv.x + ew2.x * attn_ew[0] + ew2.y * attn_ew[1];
    float v1 = elv.y + erv.y + ew2.x * attn_ew[2] + ew2.y * attn_ew[3];
    v0 = v0 >= 0.f ? v0 : NEG_SLOPE * v0;
    v1 = v1 >= 0.f ? v1 : NEG_SLOPE * v1;
    float ee0 = __expf(v0);
    float ee1 = __expf(v1);
    unsigned pk = ((unsigned)f2bf(ee1) << 16) | (unsigned)f2bf(ee0);
    uint2 rec = make_uint2((unsigned)s, pk);
    uint2* bin = edata + (size_t)d * CAP;
    int sh = e & 1;
    int pos = atomicAdd(cursor + (size_t)sh * N + d, 1);
    if (pos < SCAP) {
        bin[sh * SCAP + pos] = rec;
    } else {
        sh ^= 1;                           // retry sibling shard
        int pos2 = atomicAdd(cursor + (size_t)sh * N + d, 1);
        if (pos2 < SCAP) {
            bin[sh * SCAP + pos2] = rec;
        } else {
            int o = atomicAdd(ovfcnt, 1);
            if (o < OVFCAP)
                ovf[o] = make_float4(__int_as_float(d), __int_as_float(s), ee0, ee1);
        }
    }
}

// ---------- K3: wave-per-node gather-aggregate + normalize + residual + elu ----------
// Half-wave edge split (r4) + EXPLICIT 8-deep gather batching: per chunk,
// (1) load 8 records (independent 8B loads), (2) issue all 8 512B gathers
// into a static-indexed vv[8] (compile-time indices, no scratch), (3) fma.
// r4's VGPR=36 proved the compiler held only ~4 gathers in flight; this
// forces ~16 outstanding VMEM ops per wave. Invalid slots read row 0
// (L1-broadcast, weight 0). Avg degree 16 -> hm~8 -> one chunk per node.
__global__ __launch_bounds__(256) void aggregate(const unsigned short* __restrict__ ftb,
                                                 const float* __restrict__ feat,
                                                 const uint2* __restrict__ edata,
                                                 const int* __restrict__ cursor,
                                                 const int* __restrict__ ovfcnt,
                                                 const float4* __restrict__ ovf,
                                                 float* __restrict__ out, int N) {
    const int t = threadIdx.x;
    const int w = t >> 6, l = t & 63;
    const int n = blockIdx.x * 4 + w;
    if (n >= N) return;
    const int hl = l & 31;           // half-lane id
    const int half = l >> 5;         // 0: even edges, 1: odd edges
    const int c8 = 8 * hl;           // 8-col base this half-lane covers
    const int h = hl >> 4;           // head for these cols
    const int c0c = cursor[n], c1c = cursor[N + n];
    const int cnt0 = c0c < SCAP ? c0c : SCAP;
    const int cnt1 = c1c < SCAP ? c1c : SCAP;
    const int cnt = cnt0 + cnt1;
    const uint2* eb = edata + (size_t)n * CAP;
    const unsigned short* ftbc = ftb + c8;

    float4 a0 = make_float4(0.f, 0.f, 0.f, 0.f);
    float4 a1 = make_float4(0.f, 0.f, 0.f, 0.f);
    float dn = 0.f;
    const int hm = (cnt + 1) >> 1;
    for (int cb = 0; cb < hm; cb += 8) {
        uint2 rc[8];
#pragma unroll
        for (int k = 0; k < 8; ++k) {
            const int j = 2 * (cb + k) + half;
            const bool vld = j < cnt;
            const int jj = j < cnt0 ? j : j - cnt0 + SCAP;   // skip shard-0 pad
            rc[k] = vld ? eb[jj] : make_uint2(0u, 0u);       // weight bf16(0)=0
        }
        ushort8v vv[8];
#pragma unroll
        for (int k = 0; k < 8; ++k)
            vv[k] = *(const ushort8v*)(ftbc + (size_t)rc[k].x * 256);
#pragma unroll
        for (int k = 0; k < 8; ++k) {
            const float a = bf2f((unsigned short)(h ? (rc[k].y >> 16)
                                                    : (rc[k].y & 0xFFFFu)));
            dn += a;
            a0.x = fmaf(a, bf2f(vv[k][0]), a0.x);
            a0.y = fmaf(a, bf2f(vv[k][1]), a0.y);
            a0.z = fmaf(a, bf2f(vv[k][2]), a0.z);
            a0.w = fmaf(a, bf2f(vv[k][3]), a0.w);
            a1.x = fmaf(a, bf2f(vv[k][4]), a1.x);
            a1.y = fmaf(a, bf2f(vv[k][5]), a1.y);
            a1.z = fmaf(a, bf2f(vv[k][6]), a1.z);
            a1.w = fmaf(a, bf2f(vv[k][7]), a1.w);
        }
    }
    // combine even/odd halves (lanes l and l^32 cover the same 8 cols)
    a0.x += __shfl_xor(a0.x, 32, 64);
    a0.y += __shfl_xor(a0.y, 32, 64);
    a0.z += __shfl_xor(a0.z, 32, 64);
    a0.w += __shfl_xor(a0.w, 32, 64);
    a1.x += __shfl_xor(a1.x, 32, 64);
    a1.y += __shfl_xor(a1.y, 32, 64);
    a1.z += __shfl_xor(a1.z, 32, 64);
    a1.w += __shfl_xor(a1.w, 32, 64);
    dn += __shfl_xor(dn, 32, 64);

    if (c0c > SCAP && c1c > SCAP) {   // both shards overflowed -> exact path
        int no = *ovfcnt; if (no > OVFCAP) no = OVFCAP;   // all lanes add identically
        for (int i = 0; i < no; ++i) {
            float4 ov = ovf[i];
            if (__float_as_int(ov.x) == n) {
                int s = __float_as_int(ov.y);
                float a = h ? ov.w : ov.z;
                dn += a;
                ushort8v v = *(const ushort8v*)(ftb + (size_t)s * 256 + c8);
                a0.x = fmaf(a, bf2f(v[0]), a0.x);
                a0.y = fmaf(a, bf2f(v[1]), a0.y);
                a0.z = fmaf(a, bf2f(v[2]), a0.z);
                a0.w = fmaf(a, bf2f(v[3]), a0.w);
                a1.x = fmaf(a, bf2f(v[4]), a1.x);
                a1.y = fmaf(a, bf2f(v[5]), a1.y);
                a1.z = fmaf(a, bf2f(v[6]), a1.z);
                a1.w = fmaf(a, bf2f(v[7]), a1.w);
            }
        }
    }
    float inv = dn > 0.f ? 1.0f / dn : 0.f;
    const int cb2 = c8 + 4 * half;            // this lane's 4 output cols
    float4 av = half ? a1 : a0;
    float4 f4 = *(const float4*)(feat + (size_t)n * INF + (cb2 & 127));
    float4 r;
    r.x = fmaf(av.x, inv, f4.x);
    r.y = fmaf(av.y, inv, f4.y);
    r.z = fmaf(av.z, inv, f4.z);
    r.w = fmaf(av.w, inv, f4.w);
    r.x = r.x > 0.f ? r.x : expm1f(r.x);
    r.y = r.y > 0.f ? r.y : expm1f(r.y);
    r.z = r.z > 0.f ? r.z : expm1f(r.z);
    r.w = r.w > 0.f ? r.w : expm1f(r.w);
    *(float4*)(out + (size_t)n * 256 + cb2) = r;
}

extern "C" void kernel_launch(void* const* d_in, const int* in_sizes, int n_in,
                              void* d_out, int out_size, void* d_ws, size_t ws_size,
                              hipStream_t stream) {
    const float* feat    = (const float*)d_in[0];
    const float* e_w     = (const float*)d_in[1];
    const int*   src     = (const int*)d_in[2];
    const int*   dst     = (const int*)d_in[3];
    const float* W       = (const float*)d_in[4];
    const float* attn_l  = (const float*)d_in[5];
    const float* attn_r  = (const float*)d_in[6];
    const float* attn_ew = (const float*)d_in[7];
    float* out = (float*)d_out;

    const int N = in_sizes[0] / INF;   // 50000
    const int E = in_sizes[2];         // 800000

    // workspace carve-up (all offsets 16B-aligned for these sizes)
    unsigned short* ftb = (unsigned short*)d_ws;                 // N*256 bf16   (25.6 MB)
    uint2*  edata  = (uint2*)(ftb + (size_t)N * 256);            // N*CAP        (12.8 MB)
    float*  el     = (float*)(edata + (size_t)N * CAP);          // N*2          (0.4 MB)
    float*  er     = el + (size_t)N * 2;                         // N*2          (0.4 MB)
    float*  wfold  = er + (size_t)N * 2;                         // 4*128 f      (2 KB)
    unsigned short* Wb = (unsigned short*)(wfold + 512);         // 256*128 bf16 (64 KB)
    float4* ovf    = (float4*)(Wb + 32768);                      // OVFCAP       (0.5 MB)
    int*    cursor = (int*)(ovf + OVFCAP);                       // 2N (sharded)
    int*    ovfcnt = cursor + 2 * (size_t)N;                     // 1

    const int zblk = (2 * N + 255) / 256;
    init_kernel<<<zblk + 9, 256, 0, stream>>>(cursor, ovfcnt, W, attn_l, attn_r, Wb, wfold, N);

    gemm_mfma<<<(N + 127) / 128, 256, 0, stream>>>(feat, Wb, wfold, ftb, el, er, N);

    edge_fused<<<(E + 255) / 256, 256, 0, stream>>>(el, er, e_w, src, dst, attn_ew,
                                                    cursor, ovfcnt, edata, ovf, N, E);

    aggregate<<<(N + 3) / 4, 256, 0, stream>>>(ftb, feat, edata, cursor, ovfcnt, ovf, out, N);
}

// Round 7
// 214.638 us; speedup vs baseline: 1.1522x; 1.0824x over previous
//
#include <hip/hip_runtime.h>
#include <math.h>

// Problem constants (match reference)
#define NNODES 50000
#define NEDGES 800000
#define INF 128
#define OUTF 128
#define HEADS 2
#define NEG_SLOPE 0.2f

// Padded-bin CSR (r0-proven): single cursor, CAP=32; overflow -> exact list.
#define CAP 32
#define OVFCAP 32768

__device__ __forceinline__ unsigned short f2bf(float f) {
    unsigned u = __float_as_uint(f);
    unsigned r = (u + 0x7FFFu + ((u >> 16) & 1u)) >> 16;   // RNE
    return (unsigned short)r;
}
__device__ __forceinline__ float bf2f(unsigned short b) {
    return __uint_as_float((unsigned)b << 16);
}
// 2x f32 -> packed bf16 (1 VALU op; T12 recipe)
__device__ __forceinline__ unsigned cvt_pk_bf16(float lo, float hi) {
    unsigned r;
    asm("v_cvt_pk_bf16_f32 %0, %1, %2" : "=v"(r) : "v"(lo), "v"(hi));
    return r;
}

typedef __attribute__((ext_vector_type(8))) short frag_ab;   // 8 bf16 (4 VGPRs)
typedef __attribute__((ext_vector_type(4))) float frag_cd;   // 4 fp32 acc
typedef __attribute__((ext_vector_type(8))) unsigned short ushort8v;

#define APITCH 136   // halfs per padded LDS row (272 B)

// ---------- K0: one-time param prep (9 blocks) ----------
// block 0      : wfold[vq][128]  vq=0,1: attn_l-folded W per head; 2,3: attn_r
// blocks 1..8  : Wb = bf16(W)  (32768 elems)
__global__ void init_kernel(const float* __restrict__ W,
                            const float* __restrict__ attn_l,
                            const float* __restrict__ attn_r,
                            unsigned short* __restrict__ Wb,
                            float* __restrict__ wfold) {
    const int b = blockIdx.x, t = threadIdx.x;
    if (b == 0) {
        // el[n,h] = feat[n]·wfold[h], er[n,h] = feat[n]·wfold[2+h]
        int h = t >> 7, f = t & 127;
        float sl = 0.f, sr = 0.f;
#pragma unroll 16
        for (int o = 0; o < 128; ++o) {
            float wv = W[(size_t)(h * 128 + o) * 128 + f];
            sl = fmaf(attn_l[h * 128 + o], wv, sl);
            sr = fmaf(attn_r[h * 128 + o], wv, sr);
        }
        wfold[h * 128 + f] = sl;
        wfold[(2 + h) * 128 + f] = sr;
        return;
    }
    int base = (b - 1) * 4096 + t * 16;
#pragma unroll
    for (int q = 0; q < 4; ++q) {
        float4 g = *(const float4*)(W + base + q * 4);
        ushort4 v; v.x = f2bf(g.x); v.y = f2bf(g.y); v.z = f2bf(g.z); v.w = f2bf(g.w);
        *(ushort4*)(Wb + base + q * 4) = v;
    }
}

// ---------- K1: el/er projection + cursor zeroing ----------
// 8 nodes/block, 32 lanes/node: lane lid loads feat[n][4*lid..] (coalesced
// 512B/node), 4 dots vs wfold, butterfly-reduce within the 32-group.
// Decoupling el/er from the GEMM is what lets gemm(ftb) and edge_fused
// overlap in K2 (they are independent given el/er).
__global__ __launch_bounds__(256) void prep_kernel(const float* __restrict__ feat,
                                                   const float* __restrict__ wfold,
                                                   float* __restrict__ el,
                                                   float* __restrict__ er,
                                                   int* __restrict__ cursor,
                                                   int* __restrict__ ovfcnt, int N) {
    const int t = threadIdx.x;
    const int gtid = blockIdx.x * 256 + t;
    if (gtid < N) cursor[gtid] = 0;
    if (gtid == 0) *ovfcnt = 0;
    const int lid = t & 31;
    const int n = blockIdx.x * 8 + (t >> 5);
    if (n >= N) return;
    float4 f4 = *(const float4*)(feat + (size_t)n * INF + lid * 4);
    float pd[4];
#pragma unroll
    for (int vq = 0; vq < 4; ++vq) {
        float4 wv = *(const float4*)(wfold + vq * 128 + lid * 4);
        pd[vq] = f4.x * wv.x + f4.y * wv.y + f4.z * wv.z + f4.w * wv.w;
    }
#pragma unroll
    for (int m = 1; m < 32; m <<= 1)
#pragma unroll
        for (int vq = 0; vq < 4; ++vq) pd[vq] += __shfl_xor(pd[vq], m, 64);
    if (lid == 0) {
        *(float2*)(el + (size_t)n * 2) = make_float2(pd[0], pd[1]);
        *(float2*)(er + (size_t)n * 2) = make_float2(pd[2], pd[3]);
    }
}

// ---------- K2: wave-specialized fused gemm(ftb) || edge scatter ----------
// 512 threads: waves 0-3 = r6's gemm (128 nodes/block, LDS-staged Wb,
// swapped mfma(bf,af) -> lane holds 4 consecutive j of one node row ->
// packed uint2 stores); waves 4-7 grid-stride the edges. All 512 threads
// cooperate on the one-shot Wb->LDS staging; ONE matched barrier (wave-
// uniform role split). Each CU holds a mix of MFMA-bound gemm waves and
// atomic-latency-bound edge waves -> pipes overlap (m114) instead of the
// two kernels serializing on the stream (the ~155us remainder, r0-r6).
__global__ __launch_bounds__(512) void fused_gemm_edge(
        const float* __restrict__ feat, const unsigned short* __restrict__ Wb,
        unsigned short* __restrict__ ftb,
        const float* __restrict__ el, const float* __restrict__ er,
        const float* __restrict__ e_w, const int* __restrict__ src,
        const int* __restrict__ dst, const float* __restrict__ attn_ew,
        int* __restrict__ cursor, int* __restrict__ ovfcnt,
        uint2* __restrict__ edata, float4* __restrict__ ovf,
        int N, int E) {
    __shared__ unsigned short Bs[256 * APITCH];   // 69,632 B -> 2 blocks/CU
    const int t = threadIdx.x;
    const int lane = t & 63;
    const int m16 = lane & 15, quad = lane >> 4;
    const int n0 = blockIdx.x * 128;

    frag_ab af[2][4];
    bool vr0 = false, vr1 = false;
    int r0n = 0, r1n = 0;
    if (t < 256) {   // gemm waves: A-frag loads (overlap staging below)
        const int w = t >> 6;
        r0n = n0 + w * 16 + m16;
        r1n = r0n + 64;
        vr0 = r0n < N; vr1 = r1n < N;
#pragma unroll
        for (int kc = 0; kc < 4; ++kc) {
            const int cc = kc * 32 + quad * 8;
            float4 ga0 = make_float4(0.f, 0.f, 0.f, 0.f), ga1 = ga0;
            float4 gb0 = ga0, gb1 = ga0;
            if (vr0) {
                ga0 = *(const float4*)(feat + (size_t)r0n * INF + cc);
                ga1 = *(const float4*)(feat + (size_t)r0n * INF + cc + 4);
            }
            if (vr1) {
                gb0 = *(const float4*)(feat + (size_t)r1n * INF + cc);
                gb1 = *(const float4*)(feat + (size_t)r1n * INF + cc + 4);
            }
            union { int4 i; frag_ab f; } ua, ub;
            ua.i.x = (int)cvt_pk_bf16(ga0.x, ga0.y); ua.i.y = (int)cvt_pk_bf16(ga0.z, ga0.w);
            ua.i.z = (int)cvt_pk_bf16(ga1.x, ga1.y); ua.i.w = (int)cvt_pk_bf16(ga1.z, ga1.w);
            ub.i.x = (int)cvt_pk_bf16(gb0.x, gb0.y); ub.i.y = (int)cvt_pk_bf16(gb0.z, gb0.w);
            ub.i.z = (int)cvt_pk_bf16(gb1.x, gb1.y); ub.i.w = (int)cvt_pk_bf16(gb1.z, gb1.w);
            af[0][kc] = ua.f; af[1][kc] = ub.f;
        }
    }

    // stage Wb -> Bs, all 512 threads: 4096 16B-chunks, 8 per thread
#pragma unroll
    for (int i = 0; i < 8; ++i) {
        int q = t + i * 512;             // chunk id 0..4095
        int row = q >> 4, c = q & 15;    // row 0..255, 16B chunk 0..15
        ushort8v v = *(const ushort8v*)(Wb + row * 128 + c * 8);
        *(ushort8v*)(&Bs[row * APITCH + c * 8]) = v;
    }
    __syncthreads();   // Bs ready (single, uniformly-executed barrier)

    if (t < 256) {
        // ---------------- gemm role ----------------
#pragma unroll 1
        for (int jt = 0; jt < 4; ++jt) {
            frag_cd acc[2][4];
#pragma unroll
            for (int rg = 0; rg < 2; ++rg)
#pragma unroll
                for (int nt = 0; nt < 4; ++nt) acc[rg][nt] = frag_cd{0.f, 0.f, 0.f, 0.f};
#pragma unroll
            for (int kc = 0; kc < 4; ++kc)
#pragma unroll
                for (int nt = 0; nt < 4; ++nt) {
                    frag_ab bf = *(const frag_ab*)(&Bs[(jt * 64 + nt * 16 + m16) * APITCH
                                                       + kc * 32 + quad * 8]);
                    acc[0][nt] = __builtin_amdgcn_mfma_f32_16x16x32_bf16(bf, af[0][kc],
                                                                         acc[0][nt], 0, 0, 0);
                    acc[1][nt] = __builtin_amdgcn_mfma_f32_16x16x32_bf16(bf, af[1][kc],
                                                                         acc[1][nt], 0, 0, 0);
                }
            // lane holds j = jt*64 + nt*16 + quad*4 + (0..3) of its node row
#pragma unroll
            for (int rg = 0; rg < 2; ++rg) {
                const int rr = rg ? r1n : r0n;
                if (rg ? vr1 : vr0) {
#pragma unroll
                    for (int nt = 0; nt < 4; ++nt) {
                        uint2 p;
                        p.x = cvt_pk_bf16(acc[rg][nt][0], acc[rg][nt][1]);
                        p.y = cvt_pk_bf16(acc[rg][nt][2], acc[rg][nt][3]);
                        *(uint2*)(ftb + (size_t)rr * 256 + jt * 64 + nt * 16 + quad * 4) = p;
                    }
                }
            }
        }
    } else {
        // ---------------- edge role (r0-proven body) ----------------
        const float aew0 = attn_ew[0], aew1 = attn_ew[1];
        const float aew2 = attn_ew[2], aew3 = attn_ew[3];
        const int stride = gridDim.x * 256;
        for (int e = blockIdx.x * 256 + (t - 256); e < E; e += stride) {
            int s = src[e], d = dst[e];
            float2 ew2 = *(const float2*)(e_w + (size_t)e * 2);
            float2 elv = *(const float2*)(el + (size_t)s * 2);
            float2 erv = *(const float2*)(er + (size_t)d * 2);
            float v0 = elv.x + erv.x + ew2.x * aew0 + ew2.y * aew1;
            float v1 = elv.y + erv.y + ew2.x * aew2 + ew2.y * aew3;
            v0 = v0 >= 0.f ? v0 : NEG_SLOPE * v0;
            v1 = v1 >= 0.f ? v1 : NEG_SLOPE * v1;
            float ee0 = __expf(v0);
            float ee1 = __expf(v1);
            int pos = atomicAdd(cursor + d, 1);
            if (pos < CAP) {
                unsigned pk = ((unsigned)f2bf(ee1) << 16) | (unsigned)f2bf(ee0);
                edata[(size_t)d * CAP + pos] = make_uint2((unsigned)s, pk);
            } else {
                int o = atomicAdd(ovfcnt, 1);
                if (o < OVFCAP)
                    ovf[o] = make_float4(__int_as_float(d), __int_as_float(s), ee0, ee1);
            }
        }
    }
}

// ---------- K3: wave-per-node gather-aggregate (EXACT r0 code, 65us proven) ----------
__global__ __launch_bounds__(256) void aggregate(const unsigned short* __restrict__ ftb,
                                                 const float* __restrict__ feat,
                                                 const uint2* __restrict__ edata,
                                                 const int* __restrict__ cursor,
                                                 const int* __restrict__ ovfcnt,
                                                 const float4* __restrict__ ovf,
                                                 float* __restrict__ out, int N) {
    const int t = threadIdx.x;
    const int w = t >> 6, l = t & 63;
    const int n = blockIdx.x * 4 + w;
    if (n >= N) return;
    const int c0 = 4 * l;            // this lane's 4 cols (0..252)
    const int h = l >> 5;            // lane's head
    const int cnt = cursor[n];
    const int cmain = cnt < CAP ? cnt : CAP;
    const uint2* eb = edata + (size_t)n * CAP;

    float4 acc = make_float4(0.f, 0.f, 0.f, 0.f);
    float dn = 0.f;
#pragma unroll 4
    for (int i = 0; i < cmain; ++i) {
        uint2 rec = eb[i];
        int s = (int)rec.x;
        float a = bf2f((unsigned short)(h ? (rec.y >> 16) : (rec.y & 0xFFFFu)));
        dn += a;
        ushort4 v = *(const ushort4*)(ftb + (size_t)s * 256 + c0);
        acc.x += a * bf2f(v.x);
        acc.y += a * bf2f(v.y);
        acc.z += a * bf2f(v.z);
        acc.w += a * bf2f(v.w);
    }
    if (cnt > CAP) {   // exact overflow path (rare)
        int no = *ovfcnt; if (no > OVFCAP) no = OVFCAP;
        for (int i = 0; i < no; ++i) {
            float4 ov = ovf[i];
            if (__float_as_int(ov.x) == n) {
                int s = __float_as_int(ov.y);
                float a = h ? ov.w : ov.z;
                dn += a;
                ushort4 v = *(const ushort4*)(ftb + (size_t)s * 256 + c0);
                acc.x += a * bf2f(v.x);
                acc.y += a * bf2f(v.y);
                acc.z += a * bf2f(v.z);
                acc.w += a * bf2f(v.w);
            }
        }
    }
    float inv = dn > 0.f ? 1.0f / dn : 0.f;
    float4 f4 = *(const float4*)(feat + (size_t)n * INF + (c0 & 127));
    float4 r;
    r.x = acc.x * inv + f4.x;
    r.y = acc.y * inv + f4.y;
    r.z = acc.z * inv + f4.z;
    r.w = acc.w * inv + f4.w;
    r.x = r.x > 0.f ? r.x : expm1f(r.x);
    r.y = r.y > 0.f ? r.y : expm1f(r.y);
    r.z = r.z > 0.f ? r.z : expm1f(r.z);
    r.w = r.w > 0.f ? r.w : expm1f(r.w);
    *(float4*)(out + (size_t)n * 256 + c0) = r;
}

extern "C" void kernel_launch(void* const* d_in, const int* in_sizes, int n_in,
                              void* d_out, int out_size, void* d_ws, size_t ws_size,
                              hipStream_t stream) {
    const float* feat    = (const float*)d_in[0];
    const float* e_w     = (const float*)d_in[1];
    const int*   src     = (const int*)d_in[2];
    const int*   dst     = (const int*)d_in[3];
    const float* W       = (const float*)d_in[4];
    const float* attn_l  = (const float*)d_in[5];
    const float* attn_r  = (const float*)d_in[6];
    const float* attn_ew = (const float*)d_in[7];
    float* out = (float*)d_out;

    const int N = in_sizes[0] / INF;   // 50000
    const int E = in_sizes[2];         // 800000

    // workspace carve-up (all offsets 16B-aligned for these sizes)
    unsigned short* ftb = (unsigned short*)d_ws;                 // N*256 bf16   (25.6 MB)
    uint2*  edata  = (uint2*)(ftb + (size_t)N * 256);            // N*CAP        (12.8 MB)
    float*  el     = (float*)(edata + (size_t)N * CAP);          // N*2          (0.4 MB)
    float*  er     = el + (size_t)N * 2;                         // N*2          (0.4 MB)
    float*  wfold  = er + (size_t)N * 2;                         // 4*128 f      (2 KB)
    unsigned short* Wb = (unsigned short*)(wfold + 512);         // 256*128 bf16 (64 KB)
    float4* ovf    = (float4*)(Wb + 32768);                      // OVFCAP       (0.5 MB)
    int*    cursor = (int*)(ovf + OVFCAP);                       // N
    int*    ovfcnt = cursor + N;                                 // 1

    init_kernel<<<9, 256, 0, stream>>>(W, attn_l, attn_r, Wb, wfold);

    prep_kernel<<<(N + 7) / 8, 256, 0, stream>>>(feat, wfold, el, er, cursor, ovfcnt, N);

    fused_gemm_edge<<<(N + 127) / 128, 512, 0, stream>>>(feat, Wb, ftb, el, er, e_w,
                                                         src, dst, attn_ew,
                                                         cursor, ovfcnt, edata, ovf, N, E);

    aggregate<<<(N + 3) / 4, 256, 0, stream>>>(ftb, feat, edata, cursor, ovfcnt, ovf, out, N);
}

// Round 8
// 213.640 us; speedup vs baseline: 1.1576x; 1.0047x over previous
//
#include <hip/hip_runtime.h>
#include <math.h>

// Problem constants (match reference)
#define NNODES 50000
#define NEDGES 800000
#define INF 128
#define OUTF 128
#define HEADS 2
#define NEG_SLOPE 0.2f

// Padded-bin CSR (r0-proven): single cursor per node, CAP=32; overflow -> list.
// Cursor is padded to ONE PER 64B LINE (stride 16 ints): the dense layout put
// 16 cursors per line -> ~256 serialized device-scope RMWs per line (the r7
// fused kernel's 95%-stall signature). Padded: per-line chain = node degree.
#define CAP 32
#define CSH 4            // cursor stride shift (16 ints = 64 B)
#define OVFCAP 32768

__device__ __forceinline__ unsigned short f2bf(float f) {
    unsigned u = __float_as_uint(f);
    unsigned r = (u + 0x7FFFu + ((u >> 16) & 1u)) >> 16;   // RNE
    return (unsigned short)r;
}
__device__ __forceinline__ float bf2f(unsigned short b) {
    return __uint_as_float((unsigned)b << 16);
}
// 2x f32 -> packed bf16 (1 VALU op; T12 recipe)
__device__ __forceinline__ unsigned cvt_pk_bf16(float lo, float hi) {
    unsigned r;
    asm("v_cvt_pk_bf16_f32 %0, %1, %2" : "=v"(r) : "v"(lo), "v"(hi));
    return r;
}

typedef __attribute__((ext_vector_type(8))) short frag_ab;   // 8 bf16 (4 VGPRs)
typedef __attribute__((ext_vector_type(4))) float frag_cd;   // 4 fp32 acc
typedef __attribute__((ext_vector_type(8))) unsigned short ushort8v;

#define APITCH 136   // halfs per padded LDS row (272 B)

// ---------- K0: one-time param prep (9 blocks) ----------
// block 0      : wfold[vq][128]  vq=0,1: attn_l-folded W per head; 2,3: attn_r
// blocks 1..8  : Wb = bf16(W)  (32768 elems)
__global__ void init_kernel(const float* __restrict__ W,
                            const float* __restrict__ attn_l,
                            const float* __restrict__ attn_r,
                            unsigned short* __restrict__ Wb,
                            float* __restrict__ wfold) {
    const int b = blockIdx.x, t = threadIdx.x;
    if (b == 0) {
        // el[n,h] = feat[n]·wfold[h], er[n,h] = feat[n]·wfold[2+h]
        int h = t >> 7, f = t & 127;
        float sl = 0.f, sr = 0.f;
#pragma unroll 16
        for (int o = 0; o < 128; ++o) {
            float wv = W[(size_t)(h * 128 + o) * 128 + f];
            sl = fmaf(attn_l[h * 128 + o], wv, sl);
            sr = fmaf(attn_r[h * 128 + o], wv, sr);
        }
        wfold[h * 128 + f] = sl;
        wfold[(2 + h) * 128 + f] = sr;
        return;
    }
    int base = (b - 1) * 4096 + t * 16;
#pragma unroll
    for (int q = 0; q < 4; ++q) {
        float4 g = *(const float4*)(W + base + q * 4);
        ushort4 v; v.x = f2bf(g.x); v.y = f2bf(g.y); v.z = f2bf(g.z); v.w = f2bf(g.w);
        *(ushort4*)(Wb + base + q * 4) = v;
    }
}

// ---------- K1: el/er projection + padded-cursor zeroing ----------
// 8 nodes/block, 32 lanes/node: lane lid loads feat[n][4*lid..] (coalesced
// 512B/node), 4 dots vs wfold, butterfly-reduce within the 32-group.
__global__ __launch_bounds__(256) void prep_kernel(const float* __restrict__ feat,
                                                   const float* __restrict__ wfold,
                                                   float* __restrict__ el,
                                                   float* __restrict__ er,
                                                   int* __restrict__ cursor,
                                                   int* __restrict__ ovfcnt, int N) {
    const int t = threadIdx.x;
    const int gtid = blockIdx.x * 256 + t;
    if (gtid < (N << CSH)) cursor[gtid] = 0;     // grid 1.6M threads >= 800k slots
    if (gtid == 0) *ovfcnt = 0;
    const int lid = t & 31;
    const int n = blockIdx.x * 8 + (t >> 5);
    if (n >= N) return;
    float4 f4 = *(const float4*)(feat + (size_t)n * INF + lid * 4);
    float pd[4];
#pragma unroll
    for (int vq = 0; vq < 4; ++vq) {
        float4 wv = *(const float4*)(wfold + vq * 128 + lid * 4);
        pd[vq] = f4.x * wv.x + f4.y * wv.y + f4.z * wv.z + f4.w * wv.w;
    }
#pragma unroll
    for (int m = 1; m < 32; m <<= 1)
#pragma unroll
        for (int vq = 0; vq < 4; ++vq) pd[vq] += __shfl_xor(pd[vq], m, 64);
    if (lid == 0) {
        *(float2*)(el + (size_t)n * 2) = make_float2(pd[0], pd[1]);
        *(float2*)(er + (size_t)n * 2) = make_float2(pd[2], pd[3]);
    }
}

// ---------- K2: wave-specialized fused gemm(ftb) || edge scatter (r7) ----------
// 512 threads: waves 0-3 gemm (128 nodes/block, LDS-staged Wb, swapped
// mfma(bf,af), packed uint2 stores); waves 4-7 grid-stride the edges with
// 2-WAY ILP (two edges' load chains + atomics + stores in flight).
__global__ __launch_bounds__(512) void fused_gemm_edge(
        const float* __restrict__ feat, const unsigned short* __restrict__ Wb,
        unsigned short* __restrict__ ftb,
        const float* __restrict__ el, const float* __restrict__ er,
        const float* __restrict__ e_w, const int* __restrict__ src,
        const int* __restrict__ dst, const float* __restrict__ attn_ew,
        int* __restrict__ cursor, int* __restrict__ ovfcnt,
        uint2* __restrict__ edata, float4* __restrict__ ovf,
        int N, int E) {
    __shared__ unsigned short Bs[256 * APITCH];   // 69,632 B -> 2 blocks/CU
    const int t = threadIdx.x;
    const int lane = t & 63;
    const int m16 = lane & 15, quad = lane >> 4;
    const int n0 = blockIdx.x * 128;

    frag_ab af[2][4];
    bool vr0 = false, vr1 = false;
    int r0n = 0, r1n = 0;
    if (t < 256) {   // gemm waves: A-frag loads (overlap staging below)
        const int w = t >> 6;
        r0n = n0 + w * 16 + m16;
        r1n = r0n + 64;
        vr0 = r0n < N; vr1 = r1n < N;
#pragma unroll
        for (int kc = 0; kc < 4; ++kc) {
            const int cc = kc * 32 + quad * 8;
            float4 ga0 = make_float4(0.f, 0.f, 0.f, 0.f), ga1 = ga0;
            float4 gb0 = ga0, gb1 = ga0;
            if (vr0) {
                ga0 = *(const float4*)(feat + (size_t)r0n * INF + cc);
                ga1 = *(const float4*)(feat + (size_t)r0n * INF + cc + 4);
            }
            if (vr1) {
                gb0 = *(const float4*)(feat + (size_t)r1n * INF + cc);
                gb1 = *(const float4*)(feat + (size_t)r1n * INF + cc + 4);
            }
            union { int4 i; frag_ab f; } ua, ub;
            ua.i.x = (int)cvt_pk_bf16(ga0.x, ga0.y); ua.i.y = (int)cvt_pk_bf16(ga0.z, ga0.w);
            ua.i.z = (int)cvt_pk_bf16(ga1.x, ga1.y); ua.i.w = (int)cvt_pk_bf16(ga1.z, ga1.w);
            ub.i.x = (int)cvt_pk_bf16(gb0.x, gb0.y); ub.i.y = (int)cvt_pk_bf16(gb0.z, gb0.w);
            ub.i.z = (int)cvt_pk_bf16(gb1.x, gb1.y); ub.i.w = (int)cvt_pk_bf16(gb1.z, gb1.w);
            af[0][kc] = ua.f; af[1][kc] = ub.f;
        }
    }

    // stage Wb -> Bs, all 512 threads: 4096 16B-chunks, 8 per thread
#pragma unroll
    for (int i = 0; i < 8; ++i) {
        int q = t + i * 512;             // chunk id 0..4095
        int row = q >> 4, c = q & 15;    // row 0..255, 16B chunk 0..15
        ushort8v v = *(const ushort8v*)(Wb + row * 128 + c * 8);
        *(ushort8v*)(&Bs[row * APITCH + c * 8]) = v;
    }
    __syncthreads();   // Bs ready (single, uniformly-executed barrier)

    if (t < 256) {
        // ---------------- gemm role ----------------
#pragma unroll 1
        for (int jt = 0; jt < 4; ++jt) {
            frag_cd acc[2][4];
#pragma unroll
            for (int rg = 0; rg < 2; ++rg)
#pragma unroll
                for (int nt = 0; nt < 4; ++nt) acc[rg][nt] = frag_cd{0.f, 0.f, 0.f, 0.f};
#pragma unroll
            for (int kc = 0; kc < 4; ++kc)
#pragma unroll
                for (int nt = 0; nt < 4; ++nt) {
                    frag_ab bf = *(const frag_ab*)(&Bs[(jt * 64 + nt * 16 + m16) * APITCH
                                                       + kc * 32 + quad * 8]);
                    acc[0][nt] = __builtin_amdgcn_mfma_f32_16x16x32_bf16(bf, af[0][kc],
                                                                         acc[0][nt], 0, 0, 0);
                    acc[1][nt] = __builtin_amdgcn_mfma_f32_16x16x32_bf16(bf, af[1][kc],
                                                                         acc[1][nt], 0, 0, 0);
                }
            // lane holds j = jt*64 + nt*16 + quad*4 + (0..3) of its node row
#pragma unroll
            for (int rg = 0; rg < 2; ++rg) {
                const int rr = rg ? r1n : r0n;
                if (rg ? vr1 : vr0) {
#pragma unroll
                    for (int nt = 0; nt < 4; ++nt) {
                        uint2 p;
                        p.x = cvt_pk_bf16(acc[rg][nt][0], acc[rg][nt][1]);
                        p.y = cvt_pk_bf16(acc[rg][nt][2], acc[rg][nt][3]);
                        *(uint2*)(ftb + (size_t)rr * 256 + jt * 64 + nt * 16 + quad * 4) = p;
                    }
                }
            }
        }
    } else {
        // ---------------- edge role: 2-way ILP grid-stride ----------------
        const float aew0 = attn_ew[0], aew1 = attn_ew[1];
        const float aew2 = attn_ew[2], aew3 = attn_ew[3];
        const int stride = gridDim.x * 256;
        for (int e0 = blockIdx.x * 256 + (t - 256); e0 < E; e0 += 2 * stride) {
            const int e1 = e0 + stride;
            const bool b1 = e1 < E;
            // independent load chains for both edges
            int s0 = src[e0], d0 = dst[e0];
            int s1 = b1 ? src[e1] : 0, d1 = b1 ? dst[e1] : 0;
            float2 w0 = *(const float2*)(e_w + (size_t)e0 * 2);
            float2 w1 = b1 ? *(const float2*)(e_w + (size_t)e1 * 2)
                           : make_float2(0.f, 0.f);
            float2 el0 = *(const float2*)(el + (size_t)s0 * 2);
            float2 er0 = *(const float2*)(er + (size_t)d0 * 2);
            float2 el1 = *(const float2*)(el + (size_t)s1 * 2);
            float2 er1 = *(const float2*)(er + (size_t)d1 * 2);
            float v00 = el0.x + er0.x + w0.x * aew0 + w0.y * aew1;
            float v01 = el0.y + er0.y + w0.x * aew2 + w0.y * aew3;
            float v10 = el1.x + er1.x + w1.x * aew0 + w1.y * aew1;
            float v11 = el1.y + er1.y + w1.x * aew2 + w1.y * aew3;
            v00 = v00 >= 0.f ? v00 : NEG_SLOPE * v00;
            v01 = v01 >= 0.f ? v01 : NEG_SLOPE * v01;
            v10 = v10 >= 0.f ? v10 : NEG_SLOPE * v10;
            v11 = v11 >= 0.f ? v11 : NEG_SLOPE * v11;
            float ee00 = __expf(v00), ee01 = __expf(v01);
            float ee10 = __expf(v10), ee11 = __expf(v11);
            // both atomics in flight together
            int pos0 = atomicAdd(cursor + ((size_t)d0 << CSH), 1);
            int pos1 = b1 ? atomicAdd(cursor + ((size_t)d1 << CSH), 1) : CAP;
            if (pos0 < CAP) {
                unsigned pk = ((unsigned)f2bf(ee01) << 16) | (unsigned)f2bf(ee00);
                edata[(size_t)d0 * CAP + pos0] = make_uint2((unsigned)s0, pk);
            } else {
                int o = atomicAdd(ovfcnt, 1);
                if (o < OVFCAP)
                    ovf[o] = make_float4(__int_as_float(d0), __int_as_float(s0), ee00, ee01);
            }
            if (b1) {
                if (pos1 < CAP) {
                    unsigned pk = ((unsigned)f2bf(ee11) << 16) | (unsigned)f2bf(ee10);
                    edata[(size_t)d1 * CAP + pos1] = make_uint2((unsigned)s1, pk);
                } else {
                    int o = atomicAdd(ovfcnt, 1);
                    if (o < OVFCAP)
                        ovf[o] = make_float4(__int_as_float(d1), __int_as_float(s1), ee10, ee11);
                }
            }
        }
    }
}

// ---------- K3: wave-per-node gather-aggregate (EXACT r0 code, 65us proven) ----------
__global__ __launch_bounds__(256) void aggregate(const unsigned short* __restrict__ ftb,
                                                 const float* __restrict__ feat,
                                                 const uint2* __restrict__ edata,
                                                 const int* __restrict__ cursor,
                                                 const int* __restrict__ ovfcnt,
                                                 const float4* __restrict__ ovf,
                                                 float* __restrict__ out, int N) {
    const int t = threadIdx.x;
    const int w = t >> 6, l = t & 63;
    const int n = blockIdx.x * 4 + w;
    if (n >= N) return;
    const int c0 = 4 * l;            // this lane's 4 cols (0..252)
    const int h = l >> 5;            // lane's head
    const int cnt = cursor[(size_t)n << CSH];
    const int cmain = cnt < CAP ? cnt : CAP;
    const uint2* eb = edata + (size_t)n * CAP;

    float4 acc = make_float4(0.f, 0.f, 0.f, 0.f);
    float dn = 0.f;
#pragma unroll 4
    for (int i = 0; i < cmain; ++i) {
        uint2 rec = eb[i];
        int s = (int)rec.x;
        float a = bf2f((unsigned short)(h ? (rec.y >> 16) : (rec.y & 0xFFFFu)));
        dn += a;
        ushort4 v = *(const ushort4*)(ftb + (size_t)s * 256 + c0);
        acc.x += a * bf2f(v.x);
        acc.y += a * bf2f(v.y);
        acc.z += a * bf2f(v.z);
        acc.w += a * bf2f(v.w);
    }
    if (cnt > CAP) {   // exact overflow path (rare)
        int no = *ovfcnt; if (no > OVFCAP) no = OVFCAP;
        for (int i = 0; i < no; ++i) {
            float4 ov = ovf[i];
            if (__float_as_int(ov.x) == n) {
                int s = __float_as_int(ov.y);
                float a = h ? ov.w : ov.z;
                dn += a;
                ushort4 v = *(const ushort4*)(ftb + (size_t)s * 256 + c0);
                acc.x += a * bf2f(v.x);
                acc.y += a * bf2f(v.y);
                acc.z += a * bf2f(v.z);
                acc.w += a * bf2f(v.w);
            }
        }
    }
    float inv = dn > 0.f ? 1.0f / dn : 0.f;
    float4 f4 = *(const float4*)(feat + (size_t)n * INF + (c0 & 127));
    float4 r;
    r.x = acc.x * inv + f4.x;
    r.y = acc.y * inv + f4.y;
    r.z = acc.z * inv + f4.z;
    r.w = acc.w * inv + f4.w;
    r.x = r.x > 0.f ? r.x : expm1f(r.x);
    r.y = r.y > 0.f ? r.y : expm1f(r.y);
    r.z = r.z > 0.f ? r.z : expm1f(r.z);
    r.w = r.w > 0.f ? r.w : expm1f(r.w);
    *(float4*)(out + (size_t)n * 256 + c0) = r;
}

extern "C" void kernel_launch(void* const* d_in, const int* in_sizes, int n_in,
                              void* d_out, int out_size, void* d_ws, size_t ws_size,
                              hipStream_t stream) {
    const float* feat    = (const float*)d_in[0];
    const float* e_w     = (const float*)d_in[1];
    const int*   src     = (const int*)d_in[2];
    const int*   dst     = (const int*)d_in[3];
    const float* W       = (const float*)d_in[4];
    const float* attn_l  = (const float*)d_in[5];
    const float* attn_r  = (const float*)d_in[6];
    const float* attn_ew = (const float*)d_in[7];
    float* out = (float*)d_out;

    const int N = in_sizes[0] / INF;   // 50000
    const int E = in_sizes[2];         // 800000

    // workspace carve-up (all offsets 16B-aligned for these sizes; ~43 MB)
    unsigned short* ftb = (unsigned short*)d_ws;                 // N*256 bf16   (25.6 MB)
    uint2*  edata  = (uint2*)(ftb + (size_t)N * 256);            // N*CAP        (12.8 MB)
    float*  el     = (float*)(edata + (size_t)N * CAP);          // N*2          (0.4 MB)
    float*  er     = el + (size_t)N * 2;                         // N*2          (0.4 MB)
    float*  wfold  = er + (size_t)N * 2;                         // 4*128 f      (2 KB)
    unsigned short* Wb = (unsigned short*)(wfold + 512);         // 256*128 bf16 (64 KB)
    float4* ovf    = (float4*)(Wb + 32768);                      // OVFCAP       (0.5 MB)
    int*    cursor = (int*)(ovf + OVFCAP);                       // N*16 (64B-padded, 3.2 MB)
    int*    ovfcnt = cursor + ((size_t)N << CSH);                // 1

    init_kernel<<<9, 256, 0, stream>>>(W, attn_l, attn_r, Wb, wfold);

    prep_kernel<<<(N + 7) / 8, 256, 0, stream>>>(feat, wfold, el, er, cursor, ovfcnt, N);

    fused_gemm_edge<<<(N + 127) / 128, 512, 0, stream>>>(feat, Wb, ftb, el, er, e_w,
                                                         src, dst, attn_ew,
                                                         cursor, ovfcnt, edata, ovf, N, E);

    aggregate<<<(N + 3) / 4, 256, 0, stream>>>(ftb, feat, edata, cursor, ovfcnt, ovf, out, N);
}